// Round 13
// baseline (152.953 us; speedup 1.0000x reference)
//
#include <hip/hip_runtime.h>
#include <math.h>

#define B_ 2
#define U_ 8
#define V_ 512
#define C_ 256
#define H_ 8
#define R_ 256
#define EPS_ 1e-6f
#define LN_EPS_ 1e-5f
#define GAIN_ 2.5f

typedef __attribute__((ext_vector_type(8))) short bf16x8;
typedef __attribute__((ext_vector_type(4))) float f32x4;
typedef unsigned short ushort_t;

__device__ __forceinline__ ushort_t f2bf(float x) {
    union { float f; unsigned u; } v; v.f = x;
    unsigned r = v.u + 0x7fffu + ((v.u >> 16) & 1u);
    return (ushort_t)(r >> 16);
}

__device__ __forceinline__ float bf2f(ushort_t h) {
    union { unsigned u; float f; } v; v.u = (unsigned)h << 16; return v.f;
}

__device__ __forceinline__ unsigned cvt_pk_bf16(float lo, float hi) {
    unsigned r;
    asm("v_cvt_pk_bf16_f32 %0, %1, %2" : "=v"(r) : "v"(lo), "v"(hi));
    return r;
}

__device__ __forceinline__ float waveReduceSum(float v) {
    #pragma unroll
    for (int m = 1; m < 64; m <<= 1) v += __shfl_xor(v, m);
    return v;
}

__device__ __forceinline__ float gelu_exact(float x) {
    return 0.5f * x * (1.f + erff(x * 0.70710678118654752f));
}

// Fused prep: blocks [0,896) fold weights (with inline modulation dots);
// blocks [896,2944) LayerNorm1 (4 rows each).
__global__ __launch_bounds__(256) void k_prep(
    const float* __restrict__ codes,
    const float* __restrict__ Wcq, const float* __restrict__ Wck,
    const float* __restrict__ Wcv, const float* __restrict__ Wc1,
    const float* __restrict__ Wc2,
    const float* __restrict__ Wq, const float* __restrict__ Wk,
    const float* __restrict__ Wv, const float* __restrict__ W1,
    const float* __restrict__ W2,
    const float* __restrict__ x, const float* __restrict__ ln1g,
    const float* __restrict__ ln1b,
    ushort_t* __restrict__ wqkvT, ushort_t* __restrict__ w1T,
    ushort_t* __restrict__ w2T, ushort_t* __restrict__ xnb) {
    int bid = blockIdx.x;
    int tid = threadIdx.x;
    if (bid >= 896) {
        int row = (bid - 896) * 4 + (tid >> 6);
        int lane = tid & 63;
        const float* xr = x + (size_t)row * C_;
        float4 v = *(const float4*)&xr[lane * 4];
        float s = v.x + v.y + v.z + v.w;
        float ss = v.x * v.x + v.y * v.y + v.z * v.z + v.w * v.w;
        s = waveReduceSum(s); ss = waveReduceSum(ss);
        float mean = s * (1.f / 256.f);
        float var = ss * (1.f / 256.f) - mean * mean;
        float rstd = rsqrtf(var + LN_EPS_);
        float4 gg = *(const float4*)&ln1g[lane * 4];
        float4 bb = *(const float4*)&ln1b[lane * 4];
        uint2 pk;
        pk.x = (unsigned)f2bf((v.x - mean) * rstd * gg.x + bb.x)
             | ((unsigned)f2bf((v.y - mean) * rstd * gg.y + bb.y) << 16);
        pk.y = (unsigned)f2bf((v.z - mean) * rstd * gg.z + bb.z)
             | ((unsigned)f2bf((v.w - mean) * rstd * gg.w + bb.w) << 16);
        *(uint2*)&xnb[(size_t)row * C_ + lane * 4] = pk;
        return;
    }
    __shared__ float mpart[4][64];
    __shared__ float mrow[64];
    __shared__ ushort_t T[64][65];
    int id = bid;
    const float* W; int ldw, modIdx, colAdd, tilesPerU, base;
    ushort_t* dst; int dstCols;
    if (id < 256)      { base = 0;   W = Wq; ldw = 512; modIdx = 0; colAdd = 0;    dst = wqkvT; dstCols = 1280; tilesPerU = 32; }
    else if (id < 512) { base = 256; W = Wk; ldw = 512; modIdx = 1; colAdd = 512;  dst = wqkvT; dstCols = 1280; tilesPerU = 32; }
    else if (id < 640) { base = 512; W = Wv; ldw = 256; modIdx = 2; colAdd = 1024; dst = wqkvT; dstCols = 1280; tilesPerU = 16; }
    else if (id < 768) { base = 640; W = W1; ldw = 256; modIdx = 3; colAdd = 0;    dst = w1T;  dstCols = 256;  tilesPerU = 16; }
    else               { base = 768; W = W2; ldw = 256; modIdx = 4; colAdd = 0;    dst = w2T;  dstCols = 256;  tilesPerU = 16; }
    const float* Wc = (modIdx == 0) ? Wcq : (modIdx == 1) ? Wck :
                      (modIdx == 2) ? Wcv : (modIdx == 3) ? Wc1 : Wc2;
    int local = id - base;
    int u = local / tilesPerU;
    int t = local % tilesPerU;
    int nColTiles = ldw / 64;
    int c0 = (t / nColTiles) * 64;
    int col0 = (t % nColTiles) * 64;
    {
        const float* cd = codes + u * 192;
        int cc = tid & 63, g = tid >> 6;
        float accm = 0.f;
        #pragma unroll 4
        for (int jj = 0; jj < 48; ++jj) {
            int j = g * 48 + jj;
            accm = fmaf(cd[j], Wc[j * 256 + c0 + cc], accm);
        }
        mpart[g][cc] = accm;
        __syncthreads();
        if (tid < 64)
            mrow[tid] = 1.f + mpart[0][tid] + mpart[1][tid] + mpart[2][tid] + mpart[3][tid];
        __syncthreads();
    }
    int cl = tid >> 4;
    int cg = (tid & 15) * 4;
    #pragma unroll
    for (int it = 0; it < 4; ++it) {
        int c = cl + it * 16;
        float m = mrow[c];
        float4 wv = *(const float4*)&W[(size_t)(c0 + c) * ldw + col0 + cg];
        T[c][cg + 0] = f2bf(wv.x * m);
        T[c][cg + 1] = f2bf(wv.y * m);
        T[c][cg + 2] = f2bf(wv.z * m);
        T[c][cg + 3] = f2bf(wv.w * m);
    }
    __syncthreads();
    int j = tid >> 2;
    int ch = (tid & 3) * 16;
    ushort_t tmp[16];
    #pragma unroll
    for (int i = 0; i < 16; ++i) tmp[i] = T[ch + i][j];
    ushort_t* o = dst + ((size_t)u * dstCols + colAdd + col0 + j) * 256 + c0 + ch;
    *(bf16x8*)&o[0] = *(const bf16x8*)&tmp[0];
    *(bf16x8*)&o[8] = *(const bf16x8*)&tmp[8];
}

// QKV GEMM, 128x128 tiles, register-double-buffered K-loop.
// Register-blocked inner loop: 16 LDS reads per k-step (was 40).
__global__ __launch_bounds__(256) void k_qkv(
    const ushort_t* __restrict__ X, const ushort_t* __restrict__ WT,
    const float* __restrict__ bv, ushort_t* __restrict__ out,
    ushort_t* __restrict__ vT) {
    __shared__ __align__(16) ushort_t smem[2 * 128 * 72];
    ushort_t (*xs)[72] = (ushort_t (*)[72])smem;
    ushort_t (*wt)[72] = (ushort_t (*)[72])(smem + 128 * 72);
    int col0 = blockIdx.x * 128;
    int row0 = blockIdx.y * 128;
    int u = (row0 >> 9) & 7;
    const ushort_t* Wu = WT + (size_t)(u * 1280 + col0) * 256;
    int tid = threadIdx.x;
    int w = tid >> 6, l = tid & 63;
    int lr = l & 15, lg = l >> 4;
    int wm = w >> 1, wn = w & 1;
    f32x4 acc[4][4] = {};
    int sr = tid >> 3, sko = (tid & 7) * 8;
    bf16x8 xr[4], wr[4];
    #pragma unroll
    for (int it = 0; it < 4; ++it) {
        xr[it] = *(const bf16x8*)&X[(size_t)(row0 + sr + it * 32) * 256 + sko];
        wr[it] = *(const bf16x8*)&Wu[(size_t)(sr + it * 32) * 256 + sko];
    }
    for (int t = 0; t < 4; ++t) {
        #pragma unroll
        for (int it = 0; it < 4; ++it) {
            *(bf16x8*)&xs[sr + it * 32][sko] = xr[it];
            *(bf16x8*)&wt[sr + it * 32][sko] = wr[it];
        }
        __syncthreads();
        if (t < 3) {
            int k0 = (t + 1) * 64;
            #pragma unroll
            for (int it = 0; it < 4; ++it) {
                xr[it] = *(const bf16x8*)&X[(size_t)(row0 + sr + it * 32) * 256 + k0 + sko];
                wr[it] = *(const bf16x8*)&Wu[(size_t)(sr + it * 32) * 256 + k0 + sko];
            }
        }
        // register-block the A fragments (8 reads), then 8 B reads x 4 MFMAs each
        bf16x8 af[2][4];
        #pragma unroll
        for (int kk = 0; kk < 2; ++kk)
            #pragma unroll
            for (int m = 0; m < 4; ++m)
                af[kk][m] = *(const bf16x8*)&xs[wm * 64 + m * 16 + lr][kk * 32 + lg * 8];
        #pragma unroll
        for (int n = 0; n < 4; ++n) {
            #pragma unroll
            for (int kk = 0; kk < 2; ++kk) {
                bf16x8 bb = *(const bf16x8*)&wt[wn * 64 + n * 16 + lr][kk * 32 + lg * 8];
                #pragma unroll
                for (int m = 0; m < 4; ++m)
                    acc[m][n] = __builtin_amdgcn_mfma_f32_16x16x32_bf16(af[kk][m], bb, acc[m][n], 0, 0, 0);
            }
        }
        __syncthreads();
    }
    if (col0 < 1024) {
        #pragma unroll
        for (int m = 0; m < 4; ++m) {
            int rowb = row0 + wm * 64 + m * 16 + lg * 4;
            #pragma unroll
            for (int n = 0; n < 4; ++n) {
                int col = col0 + wn * 64 + n * 16 + lr;
                #pragma unroll
                for (int i = 0; i < 4; ++i)
                    out[(size_t)(rowb + i) * 1280 + col] = f2bf(acc[m][n][i]);
            }
        }
    } else {
        ushort_t (*vbuf)[136] = (ushort_t (*)[136])smem;
        #pragma unroll
        for (int n = 0; n < 4; ++n) {
            int c = wn * 64 + n * 16 + lr;
            float bval = bv[col0 - 1024 + c];
            #pragma unroll
            for (int m = 0; m < 4; ++m) {
                int s = wm * 64 + m * 16 + lg * 4;
                uint2 pw;
                pw.x = cvt_pk_bf16(acc[m][n][0] + bval, acc[m][n][1] + bval);
                pw.y = cvt_pk_bf16(acc[m][n][2] + bval, acc[m][n][3] + bval);
                *(uint2*)&vbuf[c][s] = pw;
            }
        }
        __syncthreads();
        int bu = row0 >> 9;
        size_t grow0 = (size_t)(bu * 256 + (col0 - 1024));
        int srow = row0 & 511;
        int cc = tid >> 4, so = (tid & 15) * 8;
        #pragma unroll
        for (int it = 0; it < 8; ++it) {
            int c = cc + it * 16;
            *(bf16x8*)&vT[(grow0 + c) * 512 + srow + so] = *(const bf16x8*)&vbuf[c][so];
        }
    }
}

// Attention per (bu,h,64-row tile). Swapped QK^T; register prefetch; XCD swizzle;
// Q fragments hoisted out of the s-loop; cvt_pk P-pack; bf16 att output.
__global__ __launch_bounds__(256) void k_attn(
    const ushort_t* __restrict__ qkv, const ushort_t* __restrict__ vT,
    const float* __restrict__ aff, ushort_t* __restrict__ attB) {
    __shared__ __align__(16) ushort_t Qs[64][72];
    __shared__ __align__(16) ushort_t Ks[64][72];
    __shared__ __align__(16) ushort_t Pt[64][72];
    __shared__ __align__(16) ushort_t Vt[32][72];
    __shared__ float As[64];
    int id = blockIdx.x;
    int xcd = id & 7, sl = id >> 3;
    int bu = xcd + 8 * (sl >> 6);
    int inr = sl & 63;
    int h = inr & 7;
    int r0 = (inr >> 3) * 64;
    const ushort_t* base = qkv + (size_t)bu * 512 * 1280;
    const ushort_t* vbase = vT + (size_t)((bu * 8 + h) * 32) * 512;
    int tid = threadIdx.x;
    int w = tid >> 6, l = tid & 63;
    int lr = l & 15, lg = l >> 4;
    int sr = tid >> 3, sko = (tid & 7) * 8;
    *(bf16x8*)&Qs[sr][sko]      = *(const bf16x8*)&base[(size_t)(r0 + sr) * 1280 + h * 64 + sko];
    *(bf16x8*)&Qs[sr + 32][sko] = *(const bf16x8*)&base[(size_t)(r0 + sr + 32) * 1280 + h * 64 + sko];
    bf16x8 kr0 = *(const bf16x8*)&base[(size_t)sr * 1280 + 512 + h * 64 + sko];
    bf16x8 kr1 = *(const bf16x8*)&base[(size_t)(sr + 32) * 1280 + 512 + h * 64 + sko];
    bf16x8 vr  = *(const bf16x8*)&vbase[(size_t)sr * 512 + sko];
    float afv = (tid < 64) ? aff[bu * 512 + tid] : 0.f;
    *(bf16x8*)&Ks[sr][sko] = kr0;
    *(bf16x8*)&Ks[sr + 32][sko] = kr1;
    if (sr < 32) *(bf16x8*)&Vt[sr][sko] = vr;
    if (tid < 64) As[tid] = afv;
    __syncthreads();
    // Q fragments are invariant across the whole s-loop: hoist (2 reads total)
    bf16x8 qb0 = *(const bf16x8*)&Qs[w * 16 + lr][lg * 8];
    bf16x8 qb1 = *(const bf16x8*)&Qs[w * 16 + lr][32 + lg * 8];
    float wsum = 0.f, asum = 0.f;
    f32x4 pacc[2] = {};
    for (int t = 0; t < 8; ++t) {
        int s0n = (t + 1) * 64;
        if (t < 7) {
            kr0 = *(const bf16x8*)&base[(size_t)(s0n + sr) * 1280 + 512 + h * 64 + sko];
            kr1 = *(const bf16x8*)&base[(size_t)(s0n + sr + 32) * 1280 + 512 + h * 64 + sko];
            if (sr < 32) vr = *(const bf16x8*)&vbase[(size_t)sr * 512 + s0n + sko];
            if (tid < 64) afv = aff[bu * 512 + s0n + tid];
        }
        #pragma unroll
        for (int n = 0; n < 4; ++n) {
            f32x4 sc = {};
            bf16x8 ka0 = *(const bf16x8*)&Ks[n * 16 + lr][lg * 8];
            sc = __builtin_amdgcn_mfma_f32_16x16x32_bf16(ka0, qb0, sc, 0, 0, 0);
            bf16x8 ka1 = *(const bf16x8*)&Ks[n * 16 + lr][32 + lg * 8];
            sc = __builtin_amdgcn_mfma_f32_16x16x32_bf16(ka1, qb1, sc, 0, 0, 0);
            float4 a4 = *(const float4*)&As[n * 16 + lg * 4];
            float e0 = __expf(sc[0]), e1 = __expf(sc[1]);
            float e2 = __expf(sc[2]), e3 = __expf(sc[3]);
            wsum += (e0 + e1) + (e2 + e3);
            float ae0 = e0 * a4.x, ae1 = e1 * a4.y, ae2 = e2 * a4.z, ae3 = e3 * a4.w;
            asum += (ae0 + ae1) + (ae2 + ae3);
            uint2 pw;
            pw.x = cvt_pk_bf16(ae0, ae1);
            pw.y = cvt_pk_bf16(ae2, ae3);
            *(uint2*)&Pt[w * 16 + lr][n * 16 + lg * 4] = pw;
        }
        // PV: hoist pa per kk (2 reads), vb per (n,kk) (4 reads)
        #pragma unroll
        for (int kk = 0; kk < 2; ++kk) {
            bf16x8 pa = *(const bf16x8*)&Pt[w * 16 + lr][kk * 32 + lg * 8];
            #pragma unroll
            for (int n = 0; n < 2; ++n) {
                bf16x8 vb = *(const bf16x8*)&Vt[n * 16 + lr][kk * 32 + lg * 8];
                pacc[n] = __builtin_amdgcn_mfma_f32_16x16x32_bf16(pa, vb, pacc[n], 0, 0, 0);
            }
        }
        __syncthreads();
        if (t < 7) {
            *(bf16x8*)&Ks[sr][sko] = kr0;
            *(bf16x8*)&Ks[sr + 32][sko] = kr1;
            if (sr < 32) *(bf16x8*)&Vt[sr][sko] = vr;
            if (tid < 64) As[tid] = afv;
            __syncthreads();
        }
    }
    asum += __shfl_xor(asum, 16); asum += __shfl_xor(asum, 32);
    wsum += __shfl_xor(wsum, 16); wsum += __shfl_xor(wsum, 32);
    float ar = aff[bu * 512 + r0 + w * 16 + lr];
    float scale = ar / (ar * asum + EPS_ * wsum);
    #pragma unroll
    for (int i = 0; i < 4; ++i) {
        float sc_i = __shfl(scale, lg * 4 + i);
        int q = r0 + w * 16 + lg * 4 + i;
        ushort_t* ob = attB + ((size_t)bu * 512 + q) * 256 + h * 32;
        ob[lr]      = f2bf(pacc[0][i] * sc_i);
        ob[16 + lr] = f2bf(pacc[1][i] * sc_i);
    }
}

// Fused tail, 16 rows/block (512 blocks, 2/CU): register-blocked MLP loops.
__global__ __launch_bounds__(256) void k_tail(
    const float* __restrict__ x, const ushort_t* __restrict__ attB,
    const float* __restrict__ aff, const float* __restrict__ g2,
    const float* __restrict__ b2, const ushort_t* __restrict__ w1T,
    const ushort_t* __restrict__ w2T, const float* __restrict__ b1m,
    const float* __restrict__ b2m, float* __restrict__ outp) {
    __shared__ __align__(16) ushort_t ynL[16][264];
    __shared__ __align__(16) float aoL[16][260];
    __shared__ __align__(16) ushort_t wt[256][72];
    int r0 = blockIdx.x * 16;
    int u = (r0 >> 9) & 7;
    int tid = threadIdx.x;
    {
        int row = tid >> 4, cb = (tid & 15) * 16;
        float a = aff[r0 + row];
        const float* xr = x + (size_t)(r0 + row) * 256 + cb;
        const ushort_t* ar = attB + (size_t)(r0 + row) * 256 + cb;
        ushort_t av[16];
        *(bf16x8*)&av[0] = *(const bf16x8*)&ar[0];
        *(bf16x8*)&av[8] = *(const bf16x8*)&ar[8];
        float o[16];
        float s = 0.f, ss = 0.f;
        #pragma unroll
        for (int j = 0; j < 16; ++j) {
            float t = (1.f - a) * xr[j] + a * GAIN_ * bf2f(av[j]);
            o[j] = t; s += t; ss += t * t;
        }
        s += __shfl_xor(s, 1); s += __shfl_xor(s, 2);
        s += __shfl_xor(s, 4); s += __shfl_xor(s, 8);
        ss += __shfl_xor(ss, 1); ss += __shfl_xor(ss, 2);
        ss += __shfl_xor(ss, 4); ss += __shfl_xor(ss, 8);
        float mean = s * (1.f / 256.f);
        float var = ss * (1.f / 256.f) - mean * mean;
        float rstd = rsqrtf(var + LN_EPS_);
        #pragma unroll
        for (int j = 0; j < 16; j += 4) {
            float4 gg = *(const float4*)&g2[cb + j];
            float4 bb = *(const float4*)&b2[cb + j];
            *(float4*)&aoL[row][cb + j] = make_float4(o[j], o[j+1], o[j+2], o[j+3]);
            uint2 pk;
            pk.x = cvt_pk_bf16((o[j]   - mean) * rstd * gg.x + bb.x,
                               (o[j+1] - mean) * rstd * gg.y + bb.y);
            pk.y = cvt_pk_bf16((o[j+2] - mean) * rstd * gg.z + bb.z,
                               (o[j+3] - mean) * rstd * gg.w + bb.w);
            *(uint2*)&ynL[row][cb + j] = pk;
        }
    }
    __syncthreads();
    int w = tid >> 6, l = tid & 63, lr = l & 15, lg = l >> 4;
    int scol = tid >> 3, sko = (tid & 7) * 8;
    const ushort_t* W1u = w1T + (size_t)u * 65536;
    const ushort_t* W2u = w2T + (size_t)u * 65536;
    // ---- MLP1 (transposed), b-fragments hoisted per k-step ----
    f32x4 acc[4] = {};
    for (int k0 = 0; k0 < 256; k0 += 64) {
        #pragma unroll
        for (int it = 0; it < 8; ++it)
            *(bf16x8*)&wt[scol + it * 32][sko] =
                *(const bf16x8*)&W1u[(size_t)(scol + it * 32) * 256 + k0 + sko];
        __syncthreads();
        bf16x8 b0 = *(const bf16x8*)&ynL[lr][k0 + lg * 8];
        bf16x8 b1 = *(const bf16x8*)&ynL[lr][k0 + 32 + lg * 8];
        #pragma unroll
        for (int n = 0; n < 4; ++n) {
            bf16x8 a0 = *(const bf16x8*)&wt[w * 64 + n * 16 + lr][lg * 8];
            acc[n] = __builtin_amdgcn_mfma_f32_16x16x32_bf16(a0, b0, acc[n], 0, 0, 0);
            bf16x8 a1 = *(const bf16x8*)&wt[w * 64 + n * 16 + lr][32 + lg * 8];
            acc[n] = __builtin_amdgcn_mfma_f32_16x16x32_bf16(a1, b1, acc[n], 0, 0, 0);
        }
        __syncthreads();
    }
    #pragma unroll
    for (int n = 0; n < 4; ++n) {
        int nc = w * 64 + n * 16 + lg * 4;
        float4 bv1 = *(const float4*)&b1m[nc];
        uint2 pw;
        pw.x = cvt_pk_bf16(gelu_exact(acc[n][0] + bv1.x), gelu_exact(acc[n][1] + bv1.y));
        pw.y = cvt_pk_bf16(gelu_exact(acc[n][2] + bv1.z), gelu_exact(acc[n][3] + bv1.w));
        *(uint2*)&ynL[lr][nc] = pw;
    }
    __syncthreads();
    // ---- MLP2 (transposed) ----
    f32x4 acc2[4] = {};
    for (int k0 = 0; k0 < 256; k0 += 64) {
        #pragma unroll
        for (int it = 0; it < 8; ++it)
            *(bf16x8*)&wt[scol + it * 32][sko] =
                *(const bf16x8*)&W2u[(size_t)(scol + it * 32) * 256 + k0 + sko];
        __syncthreads();
        bf16x8 b0 = *(const bf16x8*)&ynL[lr][k0 + lg * 8];
        bf16x8 b1 = *(const bf16x8*)&ynL[lr][k0 + 32 + lg * 8];
        #pragma unroll
        for (int n = 0; n < 4; ++n) {
            bf16x8 a0 = *(const bf16x8*)&wt[w * 64 + n * 16 + lr][lg * 8];
            acc2[n] = __builtin_amdgcn_mfma_f32_16x16x32_bf16(a0, b0, acc2[n], 0, 0, 0);
            bf16x8 a1 = *(const bf16x8*)&wt[w * 64 + n * 16 + lr][32 + lg * 8];
            acc2[n] = __builtin_amdgcn_mfma_f32_16x16x32_bf16(a1, b1, acc2[n], 0, 0, 0);
        }
        __syncthreads();
    }
    int orow = r0 + lr;
    float a = aff[orow];
    #pragma unroll
    for (int n = 0; n < 4; ++n) {
        int nc = w * 64 + n * 16 + lg * 4;
        float4 bv2 = *(const float4*)&b2m[nc];
        float4 r;
        {
            float h2 = gelu_exact(acc2[n][0] + bv2.x);
            r.x = (1.f - a) * aoL[lr][nc + 0] + GAIN_ * a * a * h2;
        }
        {
            float h2 = gelu_exact(acc2[n][1] + bv2.y);
            r.y = (1.f - a) * aoL[lr][nc + 1] + GAIN_ * a * a * h2;
        }
        {
            float h2 = gelu_exact(acc2[n][2] + bv2.z);
            r.z = (1.f - a) * aoL[lr][nc + 2] + GAIN_ * a * a * h2;
        }
        {
            float h2 = gelu_exact(acc2[n][3] + bv2.w);
            r.w = (1.f - a) * aoL[lr][nc + 3] + GAIN_ * a * a * h2;
        }
        *(float4*)&outp[(size_t)orow * 256 + nc] = r;
    }
}

extern "C" void kernel_launch(void* const* d_in, const int* in_sizes, int n_in,
                              void* d_out, int out_size, void* d_ws, size_t ws_size,
                              hipStream_t stream) {
    const float* variables  = (const float*)d_in[0];
    const float* codes      = (const float*)d_in[1];
    const float* affinities = (const float*)d_in[2];
    const float* ln1_g = (const float*)d_in[3];
    const float* ln1_b = (const float*)d_in[4];
    const float* Wq  = (const float*)d_in[5];
    const float* Wcq = (const float*)d_in[6];
    const float* Wk  = (const float*)d_in[7];
    const float* Wck = (const float*)d_in[8];
    const float* Wv  = (const float*)d_in[9];
    const float* Wcv = (const float*)d_in[10];
    const float* bv  = (const float*)d_in[11];
    const float* ln2_g = (const float*)d_in[12];
    const float* ln2_b = (const float*)d_in[13];
    const float* W1  = (const float*)d_in[14];
    const float* Wc1 = (const float*)d_in[15];
    const float* b1m = (const float*)d_in[16];
    const float* W2  = (const float*)d_in[17];
    const float* Wc2 = (const float*)d_in[18];
    const float* b2m = (const float*)d_in[19];

    char* p = (char*)d_ws;
    ushort_t* attB  = (ushort_t*)p; p += 4194304;   // [8192][256] bf16
    ushort_t* xnb   = (ushort_t*)p; p += 4194304;   // [8192][256] bf16
    ushort_t* wqkvT = (ushort_t*)p; p += 5242880;   // [8][1280][256] bf16
    ushort_t* w1T   = (ushort_t*)p; p += 1048576;   // [8][256][256] bf16
    ushort_t* w2T   = (ushort_t*)p; p += 1048576;   // [8][256][256] bf16
    ushort_t* qkvb  = (ushort_t*)p; p += 20971520;  // [8192][1280] bf16 (V cols unused)
    ushort_t* vTb   = (ushort_t*)p; p += 4194304;   // [16*8][32][512] bf16
    float* outp = (float*)d_out;

    k_prep<<<2944, 256, 0, stream>>>(codes, Wcq, Wck, Wcv, Wc1, Wc2,
                                     Wq, Wk, Wv, W1, W2,
                                     variables, ln1_g, ln1_b,
                                     wqkvT, w1T, w2T, xnb);
    k_qkv<<<dim3(10, 64), 256, 0, stream>>>(xnb, wqkvT, bv, qkvb, vTb);
    k_attn<<<1024, 256, 0, stream>>>(qkvb, vTb, affinities, attB);
    k_tail<<<512, 256, 0, stream>>>(variables, attB, affinities, ln2_g, ln2_b,
                                    w1T, w2T, b1m, b2m, outp);
}